// Round 1
// baseline (1792.536 us; speedup 1.0000x reference)
//
#include <hip/hip_runtime.h>
#include <hip/hip_bf16.h>
#include <math.h>

#define N_NODES 100000
#define N_EDGES 1600000
#define ORIG    92
#define NBR     41
#define ATOM    64
#define NCONV   3
#define HFEA    128
#define NGRAPH  256
#define ZD      169           // 2*ATOM + NBR
#define TBINS   5120
#define TMAX    10.0f         // table domain [0,10]; beyond, RBF values < 3e-9

__device__ __forceinline__ float softplus_f(float x) {
    // stable: max(x,0) + log1p(exp(-|x|))
    return fmaxf(x, 0.0f) + log1pf(expf(-fabsf(x)));
}
__device__ __forceinline__ float sigmoid_f(float x) {
    return 1.0f / (1.0f + expf(-x));
}

// h = x @ W_emb + b_emb   [N,92]x[92,64]
__global__ __launch_bounds__(256) void k_embed(const float* __restrict__ x,
                                               const float* __restrict__ W,
                                               const float* __restrict__ b,
                                               float* __restrict__ h) {
    __shared__ float xt[16][ORIG];
    int n0 = blockIdx.x * 16;
    for (int i = threadIdx.x; i < 16 * ORIG; i += 256) {
        int nn = i / ORIG, kk = i - nn * ORIG;
        xt[nn][kk] = x[(n0 + nn) * ORIG + kk];
    }
    __syncthreads();
    int c = threadIdx.x & 63, jg = threadIdx.x >> 6;
    float acc[4];
    float bias = b[c];
#pragma unroll
    for (int j = 0; j < 4; ++j) acc[j] = bias;
    for (int k = 0; k < ORIG; ++k) {
        float w = W[k * ATOM + c];
#pragma unroll
        for (int j = 0; j < 4; ++j) acc[j] += xt[jg * 4 + j][k] * w;
    }
#pragma unroll
    for (int j = 0; j < 4; ++j) h[(n0 + jg * 4 + j) * ATOM + c] = acc[j];
}

// d[e] = |edge_attr[e]|
__global__ __launch_bounds__(256) void k_dist(const float* __restrict__ ea,
                                              float* __restrict__ dvec) {
    int e = blockIdx.x * 256 + threadIdx.x;
    if (e >= N_EDGES) return;
    float a = ea[3 * e], b = ea[3 * e + 1], c = ea[3 * e + 2];
    dvec[e] = sqrtf(a * a + b * b + c * c);
}

// P[n][0:64]=h@Wf_i  [64:128]=h@Wf_j  [128:192]=h@Ws_i  [192:256]=h@Ws_j
__global__ __launch_bounds__(256) void k_nodeP(const float* __restrict__ h,
                                               const float* __restrict__ Wf,
                                               const float* __restrict__ Ws,
                                               int l, float* __restrict__ P) {
    __shared__ float ht[8][ATOM];
    int n0 = blockIdx.x * 8;
    for (int i = threadIdx.x; i < 8 * ATOM; i += 256)
        ht[i >> 6][i & 63] = h[n0 * ATOM + i];
    __syncthreads();
    int cc = threadIdx.x, m = cc >> 6, c = cc & 63;
    const float* Wb = ((m & 2) ? Ws : Wf) + l * ZD * ATOM + (m & 1) * ATOM * ATOM + c;
    float acc[8] = {0, 0, 0, 0, 0, 0, 0, 0};
    for (int k = 0; k < ATOM; ++k) {
        float w = Wb[k * ATOM];
#pragma unroll
        for (int j = 0; j < 8; ++j) acc[j] += ht[j][k] * w;
    }
#pragma unroll
    for (int j = 0; j < 8; ++j) P[(size_t)(n0 + j) * 256 + cc] = acc[j];
}

// T[b][0:64] = e(d_b)@Wf_e + bf ; T[b][64:128] = e(d_b)@Ws_e + bs
__global__ __launch_bounds__(128) void k_table(const float* __restrict__ Wf,
                                               const float* __restrict__ bf,
                                               const float* __restrict__ Ws,
                                               const float* __restrict__ bs,
                                               int l, float* __restrict__ T) {
    int b = blockIdx.x, t = threadIdx.x, c = t & 63;
    float d = b * (TMAX / TBINS);
    const float* W = ((t >= 64) ? Ws : Wf) + l * ZD * ATOM + 2 * ATOM * ATOM + c;
    float acc = ((t >= 64) ? bs : bf)[l * ATOM + c];
    for (int k = 0; k < NBR; ++k) {
        float diff = d - 0.2f * k;
        acc += expf(-5.0f * diff * diff) * W[k * ATOM];
    }
    T[b * 128 + t] = acc;
}

// per-edge message + scatter-add into agg[dst]
__global__ __launch_bounds__(256) void k_edge(const int* __restrict__ ei,
                                              const float* __restrict__ dvec,
                                              const float* __restrict__ P,
                                              const float* __restrict__ T,
                                              float* __restrict__ agg) {
    int t = blockIdx.x * 256 + threadIdx.x;
    int e = t >> 6, c = t & 63;
    int src = ei[e], dst = ei[N_EDGES + e];
    float d = dvec[e];
    float tt = fminf(d * (TBINS / TMAX), (float)TBINS - 1e-3f);
    int b0 = (int)tt;
    float w = tt - (float)b0;
    const float* T0 = T + b0 * 128;
    float gate = P[(size_t)dst * 256 + c] + P[(size_t)src * 256 + 64 + c]
               + (1.0f - w) * T0[c] + w * T0[128 + c];
    float core = P[(size_t)dst * 256 + 128 + c] + P[(size_t)src * 256 + 192 + c]
               + (1.0f - w) * T0[64 + c] + w * T0[192 + c];
    float msg = sigmoid_f(gate) * softplus_f(core);
    atomicAdd(&agg[(size_t)dst * ATOM + c], msg);
}

// per-column sum & sumsq of agg
__global__ __launch_bounds__(256) void k_bnstats(const float* __restrict__ agg,
                                                 float* __restrict__ stats) {
    __shared__ float ls[256], ls2[256];
    int c = threadIdx.x & 63, rg = threadIdx.x >> 6;
    float s = 0.0f, s2 = 0.0f;
    for (int n = blockIdx.x * 4 + rg; n < N_NODES; n += gridDim.x * 4) {
        float v = agg[(size_t)n * ATOM + c];
        s += v; s2 += v * v;
    }
    ls[threadIdx.x] = s; ls2[threadIdx.x] = s2;
    __syncthreads();
    if (threadIdx.x < 64) {
        s = ls[c] + ls[64 + c] + ls[128 + c] + ls[192 + c];
        s2 = ls2[c] + ls2[64 + c] + ls2[128 + c] + ls2[192 + c];
        atomicAdd(&stats[c], s);
        atomicAdd(&stats[64 + c], s2);
    }
}

__global__ __launch_bounds__(64) void k_bnfinal(const float* __restrict__ stats,
                                                const float* __restrict__ gamma,
                                                const float* __restrict__ beta,
                                                int l, float* __restrict__ ss) {
    int c = threadIdx.x;
    const float inv = 1.0f / (float)N_NODES;
    float mu = stats[c] * inv;
    float var = stats[64 + c] * inv - mu * mu;
    float sc = gamma[l * ATOM + c] * rsqrtf(var + 1e-5f);
    ss[c] = sc;
    ss[64 + c] = beta[l * ATOM + c] - mu * sc;
}

// h = softplus(scale*agg + shift + h)
__global__ __launch_bounds__(256) void k_update(const float* __restrict__ agg,
                                                const float* __restrict__ ss,
                                                float* __restrict__ h) {
    int t = blockIdx.x * 256 + threadIdx.x;
    int c = t & 63;
    float x = ss[c] * agg[t] + ss[64 + c] + h[t];
    h[t] = softplus_f(x);
}

__global__ __launch_bounds__(256) void k_pool(const float* __restrict__ h,
                                              const int* __restrict__ batch,
                                              float* __restrict__ g) {
    int t = blockIdx.x * 256 + threadIdx.x;
    int n = t >> 6, c = t & 63;
    atomicAdd(&g[(size_t)batch[n] * ATOM + c], h[t]);
}

__global__ __launch_bounds__(128) void k_head(const float* __restrict__ g,
                                              const float* __restrict__ W1,
                                              const float* __restrict__ b1,
                                              const float* __restrict__ W2,
                                              const float* __restrict__ b2,
                                              float* __restrict__ out) {
    __shared__ float red[128];
    int gid = blockIdx.x, j = threadIdx.x;
    float acc = b1[j];
    for (int k = 0; k < ATOM; ++k) acc += g[gid * ATOM + k] * W1[k * HFEA + j];
    red[j] = softplus_f(acc) * W2[j];
    __syncthreads();
    for (int s = 64; s > 0; s >>= 1) {
        if (j < s) red[j] += red[j + s];
        __syncthreads();
    }
    if (j == 0) out[gid] = red[0] + b2[0];
}

extern "C" void kernel_launch(void* const* d_in, const int* in_sizes, int n_in,
                              void* d_out, int out_size, void* d_ws, size_t ws_size,
                              hipStream_t stream) {
    const float* x       = (const float*)d_in[0];
    const float* ea      = (const float*)d_in[1];
    const float* W_emb   = (const float*)d_in[2];
    const float* b_emb   = (const float*)d_in[3];
    const float* Wf      = (const float*)d_in[4];
    const float* bf      = (const float*)d_in[5];
    const float* Ws      = (const float*)d_in[6];
    const float* bs      = (const float*)d_in[7];
    const float* bn_g    = (const float*)d_in[8];
    const float* bn_b    = (const float*)d_in[9];
    const float* W1      = (const float*)d_in[10];
    const float* b1      = (const float*)d_in[11];
    const float* W2      = (const float*)d_in[12];
    const float* b2      = (const float*)d_in[13];
    const int*   ei      = (const int*)d_in[14];
    const int*   batch   = (const int*)d_in[15];
    float* out = (float*)d_out;

    float* ws   = (float*)d_ws;
    float* h    = ws;                       // N*64
    float* P    = h + (size_t)N_NODES * 64; // N*256
    float* agg  = P + (size_t)N_NODES * 256;// N*64
    float* dvec = agg + (size_t)N_NODES * 64;   // E
    float* T    = dvec + (size_t)N_EDGES;       // (TBINS+1)*128
    float* stats= T + (size_t)(TBINS + 1) * 128; // 128
    float* ss   = stats + 128;                   // 128
    float* g    = ss + 128;                      // NGRAPH*64

    k_embed<<<N_NODES / 16, 256, 0, stream>>>(x, W_emb, b_emb, h);
    k_dist<<<(N_EDGES + 255) / 256, 256, 0, stream>>>(ea, dvec);

    for (int l = 0; l < NCONV; ++l) {
        k_nodeP<<<N_NODES / 8, 256, 0, stream>>>(h, Wf, Ws, l, P);
        k_table<<<TBINS + 1, 128, 0, stream>>>(Wf, bf, Ws, bs, l, T);
        hipMemsetAsync(agg, 0, (size_t)N_NODES * 64 * sizeof(float), stream);
        k_edge<<<(size_t)N_EDGES * 64 / 256, 256, 0, stream>>>(ei, dvec, P, T, agg);
        hipMemsetAsync(stats, 0, 128 * sizeof(float), stream);
        k_bnstats<<<512, 256, 0, stream>>>(agg, stats);
        k_bnfinal<<<1, 64, 0, stream>>>(stats, bn_g, bn_b, l, ss);
        k_update<<<(size_t)N_NODES * 64 / 256, 256, 0, stream>>>(agg, ss, h);
    }

    hipMemsetAsync(g, 0, (size_t)NGRAPH * 64 * sizeof(float), stream);
    k_pool<<<(size_t)N_NODES * 64 / 256, 256, 0, stream>>>(h, batch, g);
    k_head<<<NGRAPH, 128, 0, stream>>>(g, W1, b1, W2, b2, out);
}